// Round 11
// baseline (256.903 us; speedup 1.0000x reference)
//
#include <hip/hip_runtime.h>

#define NB 8192
#define NT 365
#define NF 5
#define NH 10
#define NHH 5   // NH/2
#define NG 40   // 4*NH

// Quad broadcast via DPP quad_perm (within each aligned 4-lane quad).
template<int CTRL>
__device__ __forceinline__ float qb(float v) {
    return __int_as_float(
        __builtin_amdgcn_mov_dpp(__float_as_int(v), CTRL, 0xF, 0xF, true));
}
// Exchange with lane^4 (across the two quads of an 8-group).
__device__ __forceinline__ float xswap4(float v) {
    return __int_as_float(__builtin_amdgcn_ds_swizzle(__float_as_int(v), 0x101F));
}
// Pin a scalar into a VGPR. Applied to NAMED scalars (not array elements):
// the asm result is an opaque SSA value the allocator must keep live across
// the t-loop -- defeats the loop-invariant-load rematerialization that kept
// VGPR_Count at 60-68 (< the 80 weights) in r7/r9/r10.
__device__ __forceinline__ void pin(float& v) { asm volatile("" : "+v"(v)); }

// 8 lanes per batch element: lane = (half<<2)|lq.
//   lq   = gate block f,i,o,g (jnp.split order); half = hidden cols [half*5,+5)
// whh rows PERMUTED at load (own half first) so the recurrent dot consumes
// (hh, ho) directly. g-gate weights/bias pre-scaled by 2 -> uniform exp(-r)
// path (tanh(x) = 2*sigmoid(2x)-1). x-projection computed one step ahead.
// All 80 weight floats are NAMED scalars, pinned resident.
__global__ __launch_bounds__(256, 1)
void lstm_fused8s(const float* __restrict__ x,
                  const float* __restrict__ w_ih,
                  const float* __restrict__ w_hh,
                  const float* __restrict__ bias,
                  const float* __restrict__ fc_w,
                  const float* __restrict__ fc_b,
                  float* __restrict__ out)
{
    const int tid  = blockIdx.x * 256 + threadIdx.x;
    const int lq   = tid & 3;          // gate
    const int half = (tid >> 2) & 1;   // hidden half
    const int b    = tid >> 3;         // batch element

    float* h_out = out + NB;
    float* c_out = h_out + (size_t)NB * NT * NH;

    const int col0 = lq * NH + half * NHH;
    const float gs = (lq == 3) ? 2.0f : 1.0f;   // pre-scale for tanh-as-sigmoid
    const bool isg = (lq == 3);

    // ---- 80 named scalar weights ----
#define LD_WI(f,k) float wi_##f##_##k = w_ih[(f) * NG + col0 + (k)] * gs;
#define LD_WO(j,k) float wo_##j##_##k = w_hh[(half * NHH + (j)) * NG + col0 + (k)] * gs;
#define LD_WX(j,k) float wx_##j##_##k = w_hh[((1 - half) * NHH + (j)) * NG + col0 + (k)] * gs;
#define ROW5(M,r) M(r,0) M(r,1) M(r,2) M(r,3) M(r,4)
    ROW5(LD_WI,0) ROW5(LD_WI,1) ROW5(LD_WI,2) ROW5(LD_WI,3) ROW5(LD_WI,4)
    ROW5(LD_WO,0) ROW5(LD_WO,1) ROW5(LD_WO,2) ROW5(LD_WO,3) ROW5(LD_WO,4)
    ROW5(LD_WX,0) ROW5(LD_WX,1) ROW5(LD_WX,2) ROW5(LD_WX,3) ROW5(LD_WX,4)
    float bs_0 = bias[col0 + 0] * gs;
    float bs_1 = bias[col0 + 1] * gs;
    float bs_2 = bias[col0 + 2] * gs;
    float bs_3 = bias[col0 + 3] * gs;
    float bs_4 = bias[col0 + 4] * gs;

#define PIN_WI(f,k) pin(wi_##f##_##k);
#define PIN_WO(j,k) pin(wo_##j##_##k);
#define PIN_WX(j,k) pin(wx_##j##_##k);
    ROW5(PIN_WI,0) ROW5(PIN_WI,1) ROW5(PIN_WI,2) ROW5(PIN_WI,3) ROW5(PIN_WI,4)
    ROW5(PIN_WO,0) ROW5(PIN_WO,1) ROW5(PIN_WO,2) ROW5(PIN_WO,3) ROW5(PIN_WO,4)
    ROW5(PIN_WX,0) ROW5(PIN_WX,1) ROW5(PIN_WX,2) ROW5(PIN_WX,3) ROW5(PIN_WX,4)
    pin(bs_0); pin(bs_1); pin(bs_2); pin(bs_3); pin(bs_4);

    float hh[NHH], ho[NHH], c[NHH];
    #pragma unroll
    for (int k = 0; k < NHH; ++k) { hh[k] = 0.f; ho[k] = 0.f; c[k] = 0.f; }

    const float* xp = x + (size_t)b * NT * NF;
    float* hb = h_out + (size_t)b * NT * NH + half * NHH;
    float* cb = c_out + (size_t)b * NT * NH + half * NHH;
    float* sb = ((lq < 2) ? hb : cb) + ((lq & 1) ? 3 : 0);

    // xa[k] = bias + x_t . W_ih  (computed one step ahead)
    float xa[NHH];
#define XPJ(k,xs) { float a = bs_##k; \
    a = fmaf((xs)[0], wi_0_##k, a); a = fmaf((xs)[1], wi_1_##k, a); \
    a = fmaf((xs)[2], wi_2_##k, a); a = fmaf((xs)[3], wi_3_##k, a); \
    a = fmaf((xs)[4], wi_4_##k, a); xa[k] = a; }
    {
        float x0[NF];
        #pragma unroll
        for (int f = 0; f < NF; ++f) x0[f] = xp[f];
        XPJ(0,x0) XPJ(1,x0) XPJ(2,x0) XPJ(3,x0) XPJ(4,x0)
    }

    for (int t = 0; t < NT; ++t) {
        // next-step x loads issued early (consumed at loop bottom)
        float xn[NF];
        const float* xnp = xp + (size_t)((t + 1 < NT) ? (t + 1) : t) * NF;
        #pragma unroll
        for (int f = 0; f < NF; ++f) xn[f] = xnp[f];

        // ---- recurrent dot + activation: r = xa + hh.Wown + ho.Woth ----
        float y[NHH];
#define GATE(k) { float a = xa[k]; \
    a = fmaf(hh[0], wo_0_##k, a); a = fmaf(hh[1], wo_1_##k, a); \
    a = fmaf(hh[2], wo_2_##k, a); a = fmaf(hh[3], wo_3_##k, a); \
    a = fmaf(hh[4], wo_4_##k, a); \
    a = fmaf(ho[0], wx_0_##k, a); a = fmaf(ho[1], wx_1_##k, a); \
    a = fmaf(ho[2], wx_2_##k, a); a = fmaf(ho[3], wx_3_##k, a); \
    a = fmaf(ho[4], wx_4_##k, a); \
    float e = __expf(-a); \
    float s = __builtin_amdgcn_rcpf(1.0f + e); \
    y[k] = isg ? fmaf(2.0f, s, -1.0f) : s; }
        GATE(0) GATE(1) GATE(2) GATE(3) GATE(4)

        // ---- quad gate broadcast + own-half c,h update ----
        #pragma unroll
        for (int k = 0; k < NHH; ++k) {
            float yf = qb<0x00>(y[k]);   // sigmoid(f)
            float yi = qb<0x55>(y[k]);   // sigmoid(i)
            float yo = qb<0xAA>(y[k]);   // sigmoid(o)
            float tg = qb<0xFF>(y[k]);   // tanh(g)
            float cn = fmaf(yf, c[k], yi * tg);
            c[k] = cn;
            float e2 = __expf(-2.0f * cn);
            float th = fmaf(2.0f, __builtin_amdgcn_rcpf(1.0f + e2), -1.0f);
            hh[k] = yo * th;
        }

        // ---- fetch other half of h (permuted weights need no selects) ----
        #pragma unroll
        for (int k = 0; k < NHH; ++k) ho[k] = xswap4(hh[k]);

        // ---- store this lane's slice of (h,c) ----
        {
            float a0 = (lq < 2) ? hh[0] : c[0];
            float a1 = (lq < 2) ? hh[1] : c[1];
            float a2 = (lq < 2) ? hh[2] : c[2];
            float a3 = (lq < 2) ? hh[3] : c[3];
            float a4 = (lq < 2) ? hh[4] : c[4];
            sb[0] = (lq & 1) ? a3 : a0;
            sb[1] = (lq & 1) ? a4 : a1;
            if (!(lq & 1)) sb[2] = a2;
            sb += NH;
        }

        // ---- next step's x-projection (independent, fills stall slots) ----
        XPJ(0,xn) XPJ(1,xn) XPJ(2,xn) XPJ(3,xn) XPJ(4,xn)
    }

    // ---- fc head: lane (half=0,lq=0) holds h[0..4]=hh, h[5..9]=ho ----
    if ((tid & 7) == 0) {
        float acc = fc_b[0];
        #pragma unroll
        for (int k = 0; k < NHH; ++k) acc = fmaf(hh[k], fc_w[k], acc);
        #pragma unroll
        for (int k = 0; k < NHH; ++k) acc = fmaf(ho[k], fc_w[k + NHH], acc);
        out[b] = acc;
    }
}

extern "C" void kernel_launch(void* const* d_in, const int* in_sizes, int n_in,
                              void* d_out, int out_size, void* d_ws, size_t ws_size,
                              hipStream_t stream) {
    const float* x    = (const float*)d_in[0];
    const float* wih  = (const float*)d_in[1];
    const float* whh  = (const float*)d_in[2];
    const float* bias = (const float*)d_in[3];
    const float* fcw  = (const float*)d_in[4];
    const float* fcb  = (const float*)d_in[5];
    float* out = (float*)d_out;

    const int threads = NB * 8;          // 8 lanes per batch element
    const int block = 256;
    lstm_fused8s<<<threads / block, block, 0, stream>>>(x, wih, whh, bias, fcw, fcb, out);
}